// Round 1
// baseline (322.285 us; speedup 1.0000x reference)
//
#include <hip/hip_runtime.h>
#include <hip/hip_bf16.h>
#include <math.h>

// Problem constants (from reference): path_fea (131072, 64, 1, 1, 2) fp32
#define B_ROWS   131072
#define D_DIM    128          // 64 * 2
#define P_SAMP   16
#define G_GROUPS 8192         // B / P
#define NTILE    64           // G / 128 tiles per dim

typedef __bf16 bf16x8  __attribute__((ext_vector_type(8)));
typedef float  floatx4 __attribute__((ext_vector_type(4)));
typedef unsigned short u16x8 __attribute__((ext_vector_type(8)));

__device__ __forceinline__ float wave_red64(float v) {
    #pragma unroll
    for (int off = 32; off > 0; off >>= 1) v += __shfl_xor(v, off, 64);
    return v;
}

// ---------------------------------------------------------------------------
// K1: per-group centers (bf16 + fp32 sq-norm) + intra hinge sum.
// One wave per group; lane handles dims (2*lane, 2*lane+1).
// ---------------------------------------------------------------------------
__global__ __launch_bounds__(256) void k_center_intra(
    const float* __restrict__ x,          // [B, 128]
    unsigned int* __restrict__ cbf_packed, // [G, 64] 2x bf16 packed
    float* __restrict__ sq,                // [G]
    float* __restrict__ acc)               // acc[0]=inter, acc[1]=intra
{
    const int wave = threadIdx.x >> 6;
    const int lane = threadIdx.x & 63;
    const int g    = blockIdx.x * 4 + wave;

    const float* base = x + (size_t)g * (P_SAMP * D_DIM) + 2 * lane;

    float2 v[P_SAMP];
    #pragma unroll
    for (int s = 0; s < P_SAMP; ++s)
        v[s] = *(const float2*)(base + s * D_DIM);

    float cx = 0.f, cy = 0.f;
    #pragma unroll
    for (int s = 0; s < P_SAMP; ++s) { cx += v[s].x; cy += v[s].y; }
    cx *= (1.0f / P_SAMP);
    cy *= (1.0f / P_SAMP);

    // store bf16 center (packed 2x per lane, coalesced dword stores)
    unsigned int lo = __builtin_bit_cast(unsigned short, (__bf16)cx);
    unsigned int hi = __builtin_bit_cast(unsigned short, (__bf16)cy);
    cbf_packed[(size_t)g * 64 + lane] = (hi << 16) | lo;

    // 17 butterfly reductions in parallel: 16 sample distances + 1 sq-norm
    float p[P_SAMP + 1];
    #pragma unroll
    for (int s = 0; s < P_SAMP; ++s) {
        float dx = v[s].x - cx, dy = v[s].y - cy;
        p[s] = dx * dx + dy * dy;
    }
    p[P_SAMP] = cx * cx + cy * cy;

    #pragma unroll
    for (int off = 32; off > 0; off >>= 1) {
        #pragma unroll
        for (int s = 0; s <= P_SAMP; ++s) p[s] += __shfl_xor(p[s], off, 64);
    }

    if (lane == 0) {
        sq[g] = p[P_SAMP];
        float isum = 0.f;
        #pragma unroll
        for (int s = 0; s < P_SAMP; ++s) {
            float d = sqrtf(p[s]);
            float t = fmaxf(d - 0.1f, 0.f);
            isum += t * t;
        }
        atomicAdd(acc + 1, isum);
    }
}

// ---------------------------------------------------------------------------
// K2: inter hinge via bf16 MFMA gram tiles. 128x128 tile per block,
// triangular grid (bj >= bi), diagonal masked j > i.
// LDS: XOR-swizzled 16B granules, 32 KB per operand (64 KB total).
// ---------------------------------------------------------------------------
__global__ __launch_bounds__(256) void k_inter(
    const unsigned short* __restrict__ cbf,  // [G, 128] bf16 bits
    const float* __restrict__ sq,            // [G]
    float* __restrict__ acc)
{
    const int bi = blockIdx.y;   // row-tile (i)
    const int bj = blockIdx.x;   // col-tile (j)
    if (bj < bi) return;

    __shared__ u16x8 As[128 * 16];   // [row][granule^ (row&15)]
    __shared__ u16x8 Bs[128 * 16];

    const int t  = threadIdx.x;
    const int i0 = bi * 128;
    const int j0 = bj * 128;
    const u16x8* gsrc = (const u16x8*)cbf;   // 16 granules per row

    #pragma unroll
    for (int it = 0; it < 8; ++it) {
        int gidx = t + 256 * it;             // 0..2047
        int row  = gidx >> 4;
        int gg   = gidx & 15;
        int swz  = gg ^ (row & 15);
        As[row * 16 + swz] = gsrc[(size_t)(i0 + row) * 16 + gg];
        Bs[row * 16 + swz] = gsrc[(size_t)(j0 + row) * 16 + gg];
    }
    __syncthreads();

    const int wave = t >> 6;
    const int lane = t & 63;
    const int wr   = wave >> 1;   // 0..1 (64-row half of i)
    const int wc   = wave & 1;    // 0..1 (64-col half of j)
    const int lrow = lane & 15;
    const int quad = lane >> 4;

    floatx4 c[4][4] = {};   // 16 accumulator tiles of 16x16

    #pragma unroll
    for (int ks = 0; ks < 4; ++ks) {          // K = 128 in steps of 32
        const int gbase = ks * 4 + quad;      // granule = 8 bf16 of K
        bf16x8 a[4], b[4];
        #pragma unroll
        for (int mt = 0; mt < 4; ++mt) {
            int row = wr * 64 + mt * 16 + lrow;
            a[mt] = __builtin_bit_cast(bf16x8, As[row * 16 + (gbase ^ (row & 15))]);
        }
        #pragma unroll
        for (int nt = 0; nt < 4; ++nt) {
            int row = wc * 64 + nt * 16 + lrow;
            b[nt] = __builtin_bit_cast(bf16x8, Bs[row * 16 + (gbase ^ (row & 15))]);
        }
        #pragma unroll
        for (int mt = 0; mt < 4; ++mt)
            #pragma unroll
            for (int nt = 0; nt < 4; ++nt)
                c[mt][nt] = __builtin_amdgcn_mfma_f32_16x16x32_bf16(
                                a[mt], b[nt], c[mt][nt], 0, 0, 0);
    }

    // Epilogue: d2 = sq[i] + sq[j] - 2*gram; hinge on MARGIN_INTER=1.0
    const bool diag = (bi == bj);
    float hsum = 0.f;
    #pragma unroll
    for (int mt = 0; mt < 4; ++mt) {
        #pragma unroll
        for (int nt = 0; nt < 4; ++nt) {
            int ib = i0 + wr * 64 + mt * 16 + quad * 4;   // + r
            int j  = j0 + wc * 64 + nt * 16 + lrow;
            float sqj = sq[j];
            #pragma unroll
            for (int r = 0; r < 4; ++r) {
                int i = ib + r;
                if (diag && j <= i) continue;
                float d2 = fmaxf(sq[i] + sqj - 2.0f * c[mt][nt][r], 0.f);
                float d  = sqrtf(d2);
                float tt = fmaxf(1.0f - d, 0.f);
                hsum += tt * tt;
            }
        }
    }
    hsum = wave_red64(hsum);
    if (lane == 0) atomicAdd(acc + 0, hsum);
}

// ---------------------------------------------------------------------------
// K3: finalize — divide by pair counts and write the two outputs.
// ---------------------------------------------------------------------------
__global__ void k_final(const float* __restrict__ acc, float* __restrict__ out) {
    if (threadIdx.x == 0) {
        const float n_pairs = (float)G_GROUPS * (float)(G_GROUPS - 1) * 0.5f;
        out[0] = acc[0] / n_pairs;                 // inter_loss
        out[1] = acc[1] * (1.0f / (float)B_ROWS);  // intra_loss
    }
}

extern "C" void kernel_launch(void* const* d_in, const int* in_sizes, int n_in,
                              void* d_out, int out_size, void* d_ws, size_t ws_size,
                              hipStream_t stream) {
    const float* x = (const float*)d_in[0];
    float* out = (float*)d_out;

    // workspace layout
    float*        acc = (float*)d_ws;                               // 2 floats
    float*        sq  = (float*)((char*)d_ws + 256);                // 32 KB
    unsigned int* cbp = (unsigned int*)((char*)d_ws + 65536);       // 2 MB bf16 centers
    const unsigned short* cbf = (const unsigned short*)cbp;

    hipMemsetAsync(d_ws, 0, 2 * sizeof(float), stream);

    k_center_intra<<<G_GROUPS / 4, 256, 0, stream>>>(x, cbp, sq, acc);

    dim3 grid2(NTILE, NTILE);
    k_inter<<<grid2, 256, 0, stream>>>(cbf, sq, acc);

    k_final<<<1, 64, 0, stream>>>(acc, out);
}

// Round 2
// 141.587 us; speedup vs baseline: 2.2762x; 2.2762x over previous
//
#include <hip/hip_runtime.h>
#include <hip/hip_bf16.h>
#include <math.h>

// Problem constants (from reference): path_fea (131072, 64, 1, 1, 2) fp32
#define B_ROWS   131072
#define D_DIM    128          // 64 * 2
#define P_SAMP   16
#define G_GROUPS 8192         // B / P
#define TILE64   128          // G / 64  (64-row tiles per dim)
#define NTRI     8256         // TILE64*(TILE64+1)/2 triangular wave-tiles
#define K1_BLOCKS (G_GROUPS / 4)

typedef __bf16 bf16x8  __attribute__((ext_vector_type(8)));
typedef float  floatx4 __attribute__((ext_vector_type(4)));
typedef unsigned short u16x8 __attribute__((ext_vector_type(8)));

__device__ __forceinline__ float wave_red64(float v) {
    #pragma unroll
    for (int off = 32; off > 0; off >>= 1) v += __shfl_xor(v, off, 64);
    return v;
}

// ---------------------------------------------------------------------------
// K1: per-group centers (bf16 + fp32 sq-norm) + intra hinge partials.
// One wave per group; lane handles dims (2*lane, 2*lane+1).
// NO global atomics: per-block partial sums (8192 same-address atomicAdds
// were the suspected 130us serializer last round).
// ---------------------------------------------------------------------------
__global__ __launch_bounds__(256) void k_center_intra(
    const float* __restrict__ x,           // [B, 128]
    unsigned int* __restrict__ cbf_packed,  // [G, 64] 2x bf16 packed
    float* __restrict__ sq,                 // [G]
    float* __restrict__ partial)            // [K1_BLOCKS] intra partials
{
    const int wave = threadIdx.x >> 6;
    const int lane = threadIdx.x & 63;
    const int g    = blockIdx.x * 4 + wave;

    const float* base = x + (size_t)g * (P_SAMP * D_DIM) + 2 * lane;

    float2 v[P_SAMP];
    #pragma unroll
    for (int s = 0; s < P_SAMP; ++s)
        v[s] = *(const float2*)(base + s * D_DIM);

    float cx = 0.f, cy = 0.f;
    #pragma unroll
    for (int s = 0; s < P_SAMP; ++s) { cx += v[s].x; cy += v[s].y; }
    cx *= (1.0f / P_SAMP);
    cy *= (1.0f / P_SAMP);

    unsigned int lo = __builtin_bit_cast(unsigned short, (__bf16)cx);
    unsigned int hi = __builtin_bit_cast(unsigned short, (__bf16)cy);
    cbf_packed[(size_t)g * 64 + lane] = (hi << 16) | lo;

    // 17 butterfly reductions in parallel: 16 sample dists + center sq-norm
    float p[P_SAMP + 1];
    #pragma unroll
    for (int s = 0; s < P_SAMP; ++s) {
        float dx = v[s].x - cx, dy = v[s].y - cy;
        p[s] = dx * dx + dy * dy;
    }
    p[P_SAMP] = cx * cx + cy * cy;

    #pragma unroll
    for (int off = 32; off > 0; off >>= 1) {
        #pragma unroll
        for (int s = 0; s <= P_SAMP; ++s) p[s] += __shfl_xor(p[s], off, 64);
    }

    __shared__ float sh[4];
    if (lane == 0) {
        sq[g] = p[P_SAMP];
        float isum = 0.f;
        #pragma unroll
        for (int s = 0; s < P_SAMP; ++s) {
            float d = sqrtf(p[s]);
            float t = fmaxf(d - 0.1f, 0.f);
            isum += t * t;
        }
        sh[wave] = isum;
    }
    __syncthreads();
    if (threadIdx.x == 0)
        partial[blockIdx.x] = sh[0] + sh[1] + sh[2] + sh[3];
}

// ---------------------------------------------------------------------------
// K2: inter hinge. One WAVE per 64x64 triangular tile, fragments loaded
// directly from global (centers = 2MB bf16, L2-resident). No LDS, no
// barriers; hinge branch + atomic skipped when wave contributes 0 (the
// statistically-always case: min pair distance ~2.6 >> margin 1.0).
// ---------------------------------------------------------------------------
__global__ __launch_bounds__(256) void k_inter(
    const unsigned short* __restrict__ cbf,  // [G, 128] bf16 bits
    const float* __restrict__ sq,            // [G]
    float* __restrict__ acc)                 // acc[0] = inter hinge sum
{
    const int wid  = blockIdx.x * 4 + (threadIdx.x >> 6);   // 0..NTRI-1
    const int lane = threadIdx.x & 63;
    const int lrow = lane & 15;
    const int quad = lane >> 4;

    // triangular decode: row ti has tiles j=ti..127; off(i)=128i - i(i-1)/2
    double s = sqrt(128.5 * 128.5 - 2.0 * (double)wid);
    int ti = (int)(128.5 - s);
    if (ti < 0) ti = 0;
    if (ti > TILE64 - 1) ti = TILE64 - 1;
    #define TRI_OFF(i) ((i) * TILE64 - (((i) * ((i) - 1)) >> 1))
    while (ti > 0 && TRI_OFF(ti) > wid) --ti;
    while (ti < TILE64 - 1 && TRI_OFF(ti + 1) <= wid) ++ti;
    const int tj = ti + (wid - TRI_OFF(ti));
    #undef TRI_OFF

    const int i0 = ti * 64;
    const int j0 = tj * 64;
    const u16x8* gsrc = (const u16x8*)cbf;   // 16 granules of 8 bf16 per row

    // prefetch epilogue sq values (overlaps with fragment loads / MFMA)
    floatx4 sqi[4];
    float   sqj[4];
    #pragma unroll
    for (int mt = 0; mt < 4; ++mt)
        sqi[mt] = *(const floatx4*)(sq + i0 + mt * 16 + quad * 4);
    #pragma unroll
    for (int nt = 0; nt < 4; ++nt)
        sqj[nt] = sq[j0 + nt * 16 + lrow];

    floatx4 c[4][4] = {};   // 16 accumulator tiles of 16x16

    #pragma unroll
    for (int ks = 0; ks < 4; ++ks) {               // K = 128, 32 per MFMA
        const int gg = ks * 4 + quad;              // granule along K
        bf16x8 a[4], b[4];
        #pragma unroll
        for (int mt = 0; mt < 4; ++mt)
            a[mt] = __builtin_bit_cast(bf16x8,
                        gsrc[(size_t)(i0 + mt * 16 + lrow) * 16 + gg]);
        #pragma unroll
        for (int nt = 0; nt < 4; ++nt)
            b[nt] = __builtin_bit_cast(bf16x8,
                        gsrc[(size_t)(j0 + nt * 16 + lrow) * 16 + gg]);
        #pragma unroll
        for (int mt = 0; mt < 4; ++mt)
            #pragma unroll
            for (int nt = 0; nt < 4; ++nt)
                c[mt][nt] = __builtin_amdgcn_mfma_f32_16x16x32_bf16(
                                a[mt], b[nt], c[mt][nt], 0, 0, 0);
    }

    // Epilogue: d2 = sq[i]+sq[j]-2*gram; hinge nonzero only when d2 < 1.
    const bool diag = (ti == tj);
    float hsum = 0.f;
    #pragma unroll
    for (int mt = 0; mt < 4; ++mt) {
        #pragma unroll
        for (int nt = 0; nt < 4; ++nt) {
            const int ib = i0 + mt * 16 + quad * 4;
            const int j  = j0 + nt * 16 + lrow;
            #pragma unroll
            for (int r = 0; r < 4; ++r) {
                if (diag && j <= ib + r) continue;
                float d2 = sqi[mt][r] + sqj[nt] - 2.0f * c[mt][nt][r];
                if (d2 < 1.0f) {                       // rare path
                    float d = sqrtf(fmaxf(d2, 0.f));
                    float t = 1.0f - d;
                    hsum += t * t;
                }
            }
        }
    }
    // skip reduction+atomic when the whole wave contributed nothing
    if (__ballot(hsum != 0.f)) {
        hsum = wave_red64(hsum);
        if (lane == 0) atomicAdd(acc, hsum);
    }
}

// ---------------------------------------------------------------------------
// K3: reduce K1 partials, finalize both outputs.
// ---------------------------------------------------------------------------
__global__ __launch_bounds__(256) void k_final(
    const float* __restrict__ acc,
    const float* __restrict__ partial,
    float* __restrict__ out)
{
    __shared__ float sh[4];
    float s = 0.f;
    for (int i = threadIdx.x; i < K1_BLOCKS; i += 256) s += partial[i];
    s = wave_red64(s);
    const int wave = threadIdx.x >> 6;
    const int lane = threadIdx.x & 63;
    if (lane == 0) sh[wave] = s;
    __syncthreads();
    if (threadIdx.x == 0) {
        const float n_pairs = (float)G_GROUPS * (float)(G_GROUPS - 1) * 0.5f;
        out[0] = acc[0] / n_pairs;                                 // inter
        out[1] = (sh[0] + sh[1] + sh[2] + sh[3]) / (float)B_ROWS;  // intra
    }
}

extern "C" void kernel_launch(void* const* d_in, const int* in_sizes, int n_in,
                              void* d_out, int out_size, void* d_ws, size_t ws_size,
                              hipStream_t stream) {
    const float* x = (const float*)d_in[0];
    float* out = (float*)d_out;

    // workspace layout
    float*        acc     = (float*)d_ws;                          // 4 B
    float*        partial = (float*)((char*)d_ws + 256);           // 8 KB
    float*        sq      = (float*)((char*)d_ws + 16384);         // 32 KB
    unsigned int* cbp     = (unsigned int*)((char*)d_ws + 65536);  // 2 MB
    const unsigned short* cbf = (const unsigned short*)cbp;

    hipMemsetAsync(acc, 0, sizeof(float), stream);

    k_center_intra<<<K1_BLOCKS, 256, 0, stream>>>(x, cbp, sq, partial);

    k_inter<<<NTRI / 4, 256, 0, stream>>>(cbf, sq, acc);

    k_final<<<1, 256, 0, stream>>>(acc, partial, out);
}

// Round 3
// 134.861 us; speedup vs baseline: 2.3898x; 1.0499x over previous
//
#include <hip/hip_runtime.h>
#include <hip/hip_bf16.h>
#include <math.h>

// Problem constants (from reference): path_fea (131072, 64, 1, 1, 2) fp32
#define B_ROWS   131072
#define D_DIM    128          // 64 * 2
#define P_SAMP   16
#define G_GROUPS 8192         // B / P
#define TILE64   128          // G / 64  (64-row tiles per dim)
#define NTRI     8256         // TILE64*(TILE64+1)/2 triangular wave-tiles
#define K1_BLOCKS (G_GROUPS / 4)

typedef __bf16 bf16x8  __attribute__((ext_vector_type(8)));
typedef float  floatx4 __attribute__((ext_vector_type(4)));
typedef unsigned short u16x8 __attribute__((ext_vector_type(8)));

__device__ __forceinline__ float wave_red64(float v) {
    #pragma unroll
    for (int off = 32; off > 0; off >>= 1) v += __shfl_xor(v, off, 64);
    return v;
}

// ---------------------------------------------------------------------------
// K1: per-group centers (bf16 + fp32 sq-norm) + intra hinge partials.
// One wave per group. Lane t handles dims [4*(t&31), 4*(t&31)+4) of samples
// (t>>5), (t>>5)+2, ... : every wave-load is 1KB fully contiguous (float4).
// Cross-lane reductions run within 32-lane halves (5 stages) + one xor-32.
// ---------------------------------------------------------------------------
__global__ __launch_bounds__(256) void k_center_intra(
    const float* __restrict__ x,            // [B, 128]
    uint2* __restrict__ cbf_packed,          // [G, 32] 4x bf16 packed
    float* __restrict__ sq,                  // [G]
    float* __restrict__ partial,             // [K1_BLOCKS] intra partials
    float* __restrict__ acc)                 // acc[0] zeroed here
{
    const int wave = threadIdx.x >> 6;
    const int lane = threadIdx.x & 63;
    const int half = lane >> 5;      // which sample parity this lane owns
    const int c    = lane & 31;      // dim-quad index (4 dims per lane)
    const int g    = blockIdx.x * 4 + wave;

    if (blockIdx.x == 0 && threadIdx.x == 0) acc[0] = 0.f;   // K2's accumulator

    // sample s = 2*l + half, dims 4c..4c+3
    const float* base = x + (size_t)g * (P_SAMP * D_DIM) + half * D_DIM + c * 4;

    floatx4 v[8];
    #pragma unroll
    for (int l = 0; l < 8; ++l)
        v[l] = *(const floatx4*)(base + l * (2 * D_DIM));

    // center: sum my half's 8 samples, then add the other half's
    floatx4 cs = v[0];
    #pragma unroll
    for (int l = 1; l < 8; ++l) cs += v[l];
    #pragma unroll
    for (int k = 0; k < 4; ++k) cs[k] += __shfl_xor(cs[k], 32, 64);
    floatx4 ctr = cs * (1.0f / P_SAMP);

    // 9 parallel partial sums: 8 sample dists + center sq-norm
    float p[9];
    #pragma unroll
    for (int l = 0; l < 8; ++l) {
        floatx4 d = v[l] - ctr;
        p[l] = d[0]*d[0] + d[1]*d[1] + d[2]*d[2] + d[3]*d[3];
    }
    p[8] = ctr[0]*ctr[0] + ctr[1]*ctr[1] + ctr[2]*ctr[2] + ctr[3]*ctr[3];

    #pragma unroll
    for (int off = 16; off > 0; off >>= 1) {
        #pragma unroll
        for (int s = 0; s < 9; ++s) p[s] += __shfl_xor(p[s], off, 64);
    }
    // now p[l] = full 128-dim dist^2 of sample 2l+half; p[8] = |center|^2

    // store bf16 center: half 0 lanes write 8B each -> 256B coalesced row
    if (half == 0) {
        unsigned int b0 = __builtin_bit_cast(unsigned short, (__bf16)ctr[0]);
        unsigned int b1 = __builtin_bit_cast(unsigned short, (__bf16)ctr[1]);
        unsigned int b2 = __builtin_bit_cast(unsigned short, (__bf16)ctr[2]);
        unsigned int b3 = __builtin_bit_cast(unsigned short, (__bf16)ctr[3]);
        uint2 pk;
        pk.x = (b1 << 16) | b0;
        pk.y = (b3 << 16) | b2;
        cbf_packed[(size_t)g * 32 + c] = pk;
    }
    if (lane == 0) sq[g] = p[8];

    // intra hinge for my half's 8 samples, combine halves
    float isum = 0.f;
    #pragma unroll
    for (int l = 0; l < 8; ++l) {
        float d = sqrtf(p[l]);
        float t = fmaxf(d - 0.1f, 0.f);
        isum += t * t;
    }
    isum += __shfl_xor(isum, 32, 64);

    __shared__ float sh[4];
    if (lane == 0) sh[wave] = isum;
    __syncthreads();
    if (threadIdx.x == 0)
        partial[blockIdx.x] = sh[0] + sh[1] + sh[2] + sh[3];
}

// ---------------------------------------------------------------------------
// K2: inter hinge. One WAVE per 64x64 triangular tile, MFMA fragments
// loaded directly from global (centers = 2MB bf16, L2-resident). No LDS.
// Software-pipelined: fragment batches ks and ks+1 are in flight before the
// first MFMA; batch ks+2 is issued while computing ks (double buffer).
// ---------------------------------------------------------------------------
__global__ __launch_bounds__(256) void k_inter(
    const unsigned short* __restrict__ cbf,  // [G, 128] bf16 bits
    const float* __restrict__ sq,            // [G]
    float* __restrict__ acc)                 // acc[0] = inter hinge sum
{
    const int wid  = blockIdx.x * 4 + (threadIdx.x >> 6);   // 0..NTRI-1
    const int lane = threadIdx.x & 63;
    const int lrow = lane & 15;
    const int quad = lane >> 4;

    // triangular decode: row ti has tiles j=ti..127; off(i)=128i - i(i-1)/2
    double s = sqrt(128.5 * 128.5 - 2.0 * (double)wid);
    int ti = (int)(128.5 - s);
    if (ti < 0) ti = 0;
    if (ti > TILE64 - 1) ti = TILE64 - 1;
    #define TRI_OFF(i) ((i) * TILE64 - (((i) * ((i) - 1)) >> 1))
    while (ti > 0 && TRI_OFF(ti) > wid) --ti;
    while (ti < TILE64 - 1 && TRI_OFF(ti + 1) <= wid) ++ti;
    const int tj = ti + (wid - TRI_OFF(ti));
    #undef TRI_OFF

    const int i0 = ti * 64;
    const int j0 = tj * 64;
    const u16x8* gsrc = (const u16x8*)cbf;   // 16 granules of 8 bf16 per row

    // epilogue sq values first (L2 hits, retire before the frag batches)
    floatx4 sqi[4];
    float   sqj[4];
    #pragma unroll
    for (int mt = 0; mt < 4; ++mt)
        sqi[mt] = *(const floatx4*)(sq + i0 + mt * 16 + quad * 4);
    #pragma unroll
    for (int nt = 0; nt < 4; ++nt)
        sqj[nt] = sq[j0 + nt * 16 + lrow];

    // double-buffered fragment registers
    bf16x8 a[2][4], b[2][4];
    #pragma unroll
    for (int pb = 0; pb < 2; ++pb) {               // issue batches 0 and 1
        const int gg = pb * 4 + quad;
        #pragma unroll
        for (int mt = 0; mt < 4; ++mt)
            a[pb][mt] = __builtin_bit_cast(bf16x8,
                            gsrc[(size_t)(i0 + mt * 16 + lrow) * 16 + gg]);
        #pragma unroll
        for (int nt = 0; nt < 4; ++nt)
            b[pb][nt] = __builtin_bit_cast(bf16x8,
                            gsrc[(size_t)(j0 + nt * 16 + lrow) * 16 + gg]);
    }

    floatx4 c4[4][4] = {};   // 16 accumulator tiles of 16x16

    #pragma unroll
    for (int ks = 0; ks < 4; ++ks) {               // K = 128, 32 per MFMA
        const int cur = ks & 1;
        #pragma unroll
        for (int mt = 0; mt < 4; ++mt)
            #pragma unroll
            for (int nt = 0; nt < 4; ++nt)
                c4[mt][nt] = __builtin_amdgcn_mfma_f32_16x16x32_bf16(
                                a[cur][mt], b[cur][nt], c4[mt][nt], 0, 0, 0);
        if (ks < 2) {                              // refill with batch ks+2
            const int gg = (ks + 2) * 4 + quad;
            #pragma unroll
            for (int mt = 0; mt < 4; ++mt)
                a[cur][mt] = __builtin_bit_cast(bf16x8,
                                gsrc[(size_t)(i0 + mt * 16 + lrow) * 16 + gg]);
            #pragma unroll
            for (int nt = 0; nt < 4; ++nt)
                b[cur][nt] = __builtin_bit_cast(bf16x8,
                                gsrc[(size_t)(j0 + nt * 16 + lrow) * 16 + gg]);
        }
    }

    // Epilogue: d2 = sq[i]+sq[j]-2*gram; hinge nonzero only when d2 < 1.
    const bool diag = (ti == tj);
    float hsum = 0.f;
    #pragma unroll
    for (int mt = 0; mt < 4; ++mt) {
        #pragma unroll
        for (int nt = 0; nt < 4; ++nt) {
            const int ib = i0 + mt * 16 + quad * 4;
            const int j  = j0 + nt * 16 + lrow;
            #pragma unroll
            for (int r = 0; r < 4; ++r) {
                if (diag && j <= ib + r) continue;
                float d2 = sqi[mt][r] + sqj[nt] - 2.0f * c4[mt][nt][r];
                if (d2 < 1.0f) {                       // rare path
                    float d = sqrtf(fmaxf(d2, 0.f));
                    float t = 1.0f - d;
                    hsum += t * t;
                }
            }
        }
    }
    if (__ballot(hsum != 0.f)) {
        hsum = wave_red64(hsum);
        if (lane == 0) atomicAdd(acc, hsum);
    }
}

// ---------------------------------------------------------------------------
// K3: reduce K1 partials, finalize both outputs.
// ---------------------------------------------------------------------------
__global__ __launch_bounds__(256) void k_final(
    const float* __restrict__ acc,
    const float* __restrict__ partial,
    float* __restrict__ out)
{
    __shared__ float sh[4];
    float s = 0.f;
    for (int i = threadIdx.x; i < K1_BLOCKS; i += 256) s += partial[i];
    s = wave_red64(s);
    const int wave = threadIdx.x >> 6;
    const int lane = threadIdx.x & 63;
    if (lane == 0) sh[wave] = s;
    __syncthreads();
    if (threadIdx.x == 0) {
        const float n_pairs = (float)G_GROUPS * (float)(G_GROUPS - 1) * 0.5f;
        out[0] = acc[0] / n_pairs;                                 // inter
        out[1] = (sh[0] + sh[1] + sh[2] + sh[3]) / (float)B_ROWS;  // intra
    }
}

extern "C" void kernel_launch(void* const* d_in, const int* in_sizes, int n_in,
                              void* d_out, int out_size, void* d_ws, size_t ws_size,
                              hipStream_t stream) {
    const float* x = (const float*)d_in[0];
    float* out = (float*)d_out;

    // workspace layout
    float* acc     = (float*)d_ws;                          // 4 B
    float* partial = (float*)((char*)d_ws + 256);           // 8 KB
    float* sq      = (float*)((char*)d_ws + 16384);         // 32 KB
    uint2* cbp     = (uint2*)((char*)d_ws + 65536);         // 2 MB bf16 centers
    const unsigned short* cbf = (const unsigned short*)cbp;

    k_center_intra<<<K1_BLOCKS, 256, 0, stream>>>(x, cbp, sq, partial, acc);

    k_inter<<<NTRI / 4, 256, 0, stream>>>(cbf, sq, acc);

    k_final<<<1, 256, 0, stream>>>(acc, partial, out);
}

// Round 4
// 116.064 us; speedup vs baseline: 2.7768x; 1.1620x over previous
//
#include <hip/hip_runtime.h>
#include <hip/hip_bf16.h>
#include <math.h>

// Problem constants (from reference): path_fea (131072, 64, 1, 1, 2) fp32
#define B_ROWS   131072
#define D_DIM    128          // 64 * 2
#define P_SAMP   16
#define G_GROUPS 8192         // B / P
#define TILE64   128          // G / 64  (64-row tiles per dim)
#define NTRI     8256         // TILE64*(TILE64+1)/2 triangular wave-tiles
#define K1_BLOCKS (G_GROUPS / 4)

typedef __bf16 bf16x8  __attribute__((ext_vector_type(8)));
typedef float  floatx4 __attribute__((ext_vector_type(4)));
typedef unsigned short u16x8 __attribute__((ext_vector_type(8)));

// Fragment-friendly center layout (written by K1, read by K2):
//   granule index = (row>>4)*256 + gg*16 + (row&15),  gg = k-octet 0..15
//   each granule = 8 bf16 (16 B). A wave's fragment load (16 rows x 4
//   granules) is then ONE contiguous 1 KB region -> perfectly coalesced.

__device__ __forceinline__ float wave_red64(float v) {
    #pragma unroll
    for (int off = 32; off > 0; off >>= 1) v += __shfl_xor(v, off, 64);
    return v;
}

// ---------------------------------------------------------------------------
// K1: per-group centers (bf16, fragment layout) + |center|^2 + intra hinge.
// One wave per group. Lane t: dims [4*(t&31), +4) of samples (t>>5)+2l.
// All global loads are 1KB-contiguous wave-loads (float4).
// ---------------------------------------------------------------------------
__global__ __launch_bounds__(256) void k_center_intra(
    const float* __restrict__ x,            // [B, 128]
    uint2* __restrict__ cfrag,               // [G*32] 8B halves of granules
    float* __restrict__ sq,                  // [G]
    float* __restrict__ partial,             // [K1_BLOCKS] intra partials
    float* __restrict__ acc)                 // acc[0] zeroed here
{
    const int wave = threadIdx.x >> 6;
    const int lane = threadIdx.x & 63;
    const int half = lane >> 5;      // sample parity this lane owns
    const int c    = lane & 31;      // dim-quad index (4 dims per lane)
    const int g    = blockIdx.x * 4 + wave;

    if (blockIdx.x == 0 && threadIdx.x == 0) acc[0] = 0.f;   // K2's accumulator

    // sample s = 2*l + half, dims 4c..4c+3
    const float* base = x + (size_t)g * (P_SAMP * D_DIM) + half * D_DIM + c * 4;

    floatx4 v[8];
    #pragma unroll
    for (int l = 0; l < 8; ++l)
        v[l] = *(const floatx4*)(base + l * (2 * D_DIM));

    // center: sum my half's 8 samples, then add the other half's
    floatx4 cs = v[0];
    #pragma unroll
    for (int l = 1; l < 8; ++l) cs += v[l];
    #pragma unroll
    for (int k = 0; k < 4; ++k) cs[k] += __shfl_xor(cs[k], 32, 64);
    floatx4 ctr = cs * (1.0f / P_SAMP);

    // 9 parallel partial sums: 8 sample dists + center sq-norm
    float p[9];
    #pragma unroll
    for (int l = 0; l < 8; ++l) {
        floatx4 d = v[l] - ctr;
        p[l] = d[0]*d[0] + d[1]*d[1] + d[2]*d[2] + d[3]*d[3];
    }
    p[8] = ctr[0]*ctr[0] + ctr[1]*ctr[1] + ctr[2]*ctr[2] + ctr[3]*ctr[3];

    #pragma unroll
    for (int off = 16; off > 0; off >>= 1) {
        #pragma unroll
        for (int s = 0; s < 9; ++s) p[s] += __shfl_xor(p[s], off, 64);
    }
    // p[l] = full 128-dim dist^2 of sample 2l+half; p[8] = |center|^2

    // store bf16 center into fragment layout: lane c covers dims 4c..4c+3 =
    // granule gg=c>>1, half-granule c&1. 8 B per lane, half 0 only.
    if (half == 0) {
        unsigned int b0 = __builtin_bit_cast(unsigned short, (__bf16)ctr[0]);
        unsigned int b1 = __builtin_bit_cast(unsigned short, (__bf16)ctr[1]);
        unsigned int b2 = __builtin_bit_cast(unsigned short, (__bf16)ctr[2]);
        unsigned int b3 = __builtin_bit_cast(unsigned short, (__bf16)ctr[3]);
        uint2 pk;
        pk.x = (b1 << 16) | b0;
        pk.y = (b3 << 16) | b2;
        const int gran = (g >> 4) * 256 + (c >> 1) * 16 + (g & 15);
        cfrag[gran * 2 + (c & 1)] = pk;
    }
    if (lane == 0) sq[g] = p[8];

    // intra hinge for my half's 8 samples, combine halves
    float isum = 0.f;
    #pragma unroll
    for (int l = 0; l < 8; ++l) {
        float d = sqrtf(p[l]);
        float t = fmaxf(d - 0.1f, 0.f);
        isum += t * t;
    }
    isum += __shfl_xor(isum, 32, 64);

    __shared__ float sh[4];
    if (lane == 0) sh[wave] = isum;
    __syncthreads();
    if (threadIdx.x == 0)
        partial[blockIdx.x] = sh[0] + sh[1] + sh[2] + sh[3];
}

// ---------------------------------------------------------------------------
// K2: inter hinge. One WAVE per 64x64 triangular tile. Fragments come from
// the fragment-ordered center buffer: every load is a contiguous 1 KB
// wave-load (buffer_load_dwordx4, lane i at byte 16*i). Register
// double-buffer keeps 2 k-batches in flight across the MFMA groups.
// ---------------------------------------------------------------------------
__global__ __launch_bounds__(256) void k_inter(
    const u16x8* __restrict__ cfrag,         // granule array (16 B each)
    const float* __restrict__ sq,            // [G]
    float* __restrict__ acc)                 // acc[0] = inter hinge sum
{
    const int wid  = blockIdx.x * 4 + (threadIdx.x >> 6);   // 0..NTRI-1
    const int lane = threadIdx.x & 63;
    const int lrow = lane & 15;
    const int quad = lane >> 4;

    // triangular decode: row ti has tiles j=ti..127; off(i)=128i - i(i-1)/2
    double s = sqrt(128.5 * 128.5 - 2.0 * (double)wid);
    int ti = (int)(128.5 - s);
    if (ti < 0) ti = 0;
    if (ti > TILE64 - 1) ti = TILE64 - 1;
    #define TRI_OFF(i) ((i) * TILE64 - (((i) * ((i) - 1)) >> 1))
    while (ti > 0 && TRI_OFF(ti) > wid) --ti;
    while (ti < TILE64 - 1 && TRI_OFF(ti + 1) <= wid) ++ti;
    const int tj = ti + (wid - TRI_OFF(ti));
    #undef TRI_OFF

    const int i0 = ti * 64;
    const int j0 = tj * 64;

    // epilogue sq values first (L2 hits, retire before the frag batches)
    floatx4 sqi[4];
    float   sqj[4];
    #pragma unroll
    for (int mt = 0; mt < 4; ++mt)
        sqi[mt] = *(const floatx4*)(sq + i0 + mt * 16 + quad * 4);
    #pragma unroll
    for (int nt = 0; nt < 4; ++nt)
        sqj[nt] = sq[j0 + nt * 16 + lrow];

    // granule index for fragment (row-group rg, k-batch ks):
    //   rg*256 + (ks*4+quad)*16 + lrow   — contiguous across the wave
    #define FRAG_IDX(rg, ks) ((rg) * 256 + ((ks) * 4 + quad) * 16 + lrow)

    // double-buffered fragment registers
    bf16x8 a[2][4], b[2][4];
    #pragma unroll
    for (int pb = 0; pb < 2; ++pb) {               // issue batches 0 and 1
        #pragma unroll
        for (int mt = 0; mt < 4; ++mt)
            a[pb][mt] = __builtin_bit_cast(bf16x8, cfrag[FRAG_IDX(ti * 4 + mt, pb)]);
        #pragma unroll
        for (int nt = 0; nt < 4; ++nt)
            b[pb][nt] = __builtin_bit_cast(bf16x8, cfrag[FRAG_IDX(tj * 4 + nt, pb)]);
    }

    floatx4 c4[4][4] = {};   // 16 accumulator tiles of 16x16

    #pragma unroll
    for (int ks = 0; ks < 4; ++ks) {               // K = 128, 32 per MFMA
        const int cur = ks & 1;
        #pragma unroll
        for (int mt = 0; mt < 4; ++mt)
            #pragma unroll
            for (int nt = 0; nt < 4; ++nt)
                c4[mt][nt] = __builtin_amdgcn_mfma_f32_16x16x32_bf16(
                                a[cur][mt], b[cur][nt], c4[mt][nt], 0, 0, 0);
        if (ks < 2) {                              // refill with batch ks+2
            #pragma unroll
            for (int mt = 0; mt < 4; ++mt)
                a[cur][mt] = __builtin_bit_cast(bf16x8,
                                 cfrag[FRAG_IDX(ti * 4 + mt, ks + 2)]);
            #pragma unroll
            for (int nt = 0; nt < 4; ++nt)
                b[cur][nt] = __builtin_bit_cast(bf16x8,
                                 cfrag[FRAG_IDX(tj * 4 + nt, ks + 2)]);
        }
    }
    #undef FRAG_IDX

    // Epilogue: d2 = sq[i]+sq[j]-2*gram; hinge nonzero only when d2 < 1.
    const bool diag = (ti == tj);
    float hsum = 0.f;
    #pragma unroll
    for (int mt = 0; mt < 4; ++mt) {
        #pragma unroll
        for (int nt = 0; nt < 4; ++nt) {
            const int ib = i0 + mt * 16 + quad * 4;
            const int j  = j0 + nt * 16 + lrow;
            #pragma unroll
            for (int r = 0; r < 4; ++r) {
                if (diag && j <= ib + r) continue;
                float d2 = sqi[mt][r] + sqj[nt] - 2.0f * c4[mt][nt][r];
                if (d2 < 1.0f) {                       // rare path
                    float d = sqrtf(fmaxf(d2, 0.f));
                    float t = 1.0f - d;
                    hsum += t * t;
                }
            }
        }
    }
    if (__ballot(hsum != 0.f)) {
        hsum = wave_red64(hsum);
        if (lane == 0) atomicAdd(acc, hsum);
    }
}

// ---------------------------------------------------------------------------
// K3: reduce K1 partials, finalize both outputs.
// ---------------------------------------------------------------------------
__global__ __launch_bounds__(256) void k_final(
    const float* __restrict__ acc,
    const float* __restrict__ partial,
    float* __restrict__ out)
{
    __shared__ float sh[4];
    float s = 0.f;
    for (int i = threadIdx.x; i < K1_BLOCKS; i += 256) s += partial[i];
    s = wave_red64(s);
    const int wave = threadIdx.x >> 6;
    const int lane = threadIdx.x & 63;
    if (lane == 0) sh[wave] = s;
    __syncthreads();
    if (threadIdx.x == 0) {
        const float n_pairs = (float)G_GROUPS * (float)(G_GROUPS - 1) * 0.5f;
        out[0] = acc[0] / n_pairs;                                 // inter
        out[1] = (sh[0] + sh[1] + sh[2] + sh[3]) / (float)B_ROWS;  // intra
    }
}

extern "C" void kernel_launch(void* const* d_in, const int* in_sizes, int n_in,
                              void* d_out, int out_size, void* d_ws, size_t ws_size,
                              hipStream_t stream) {
    const float* x = (const float*)d_in[0];
    float* out = (float*)d_out;

    // workspace layout
    float* acc     = (float*)d_ws;                          // 4 B
    float* partial = (float*)((char*)d_ws + 256);           // 8 KB
    float* sq      = (float*)((char*)d_ws + 16384);         // 32 KB
    uint2* cfrag   = (uint2*)((char*)d_ws + 65536);         // 2 MB bf16 centers

    k_center_intra<<<K1_BLOCKS, 256, 0, stream>>>(x, cfrag, sq, partial, acc);

    k_inter<<<NTRI / 4, 256, 0, stream>>>((const u16x8*)cfrag, sq, acc);

    k_final<<<1, 256, 0, stream>>>(acc, partial, out);
}